// Round 8
// baseline (5960.170 us; speedup 1.0000x reference)
//
#include <hip/hip_runtime.h>
#include <math.h>

#define BB 2
#define DD 768
#define HH 16
#define HDIM 48
#define LL 3
#define NIMG 1024
#define NPAST 16
#define TDEC 20
#define SEQ0 1041
#define SPAD 1064
#define MM (BB*SEQ0)
#define SCALE_QK 0.14433756729740643f
#define KVL_C ((size_t)BB*HH*SPAD*HDIM)

typedef __attribute__((ext_vector_type(4))) float f32x4;
typedef __attribute__((ext_vector_type(8))) short bf16x8;

__device__ __forceinline__ short f2bf(float x) {
  unsigned u = __float_as_uint(x);
  unsigned r = (u + 0x7FFFu + ((u >> 16) & 1u)) >> 16;
  return (short)r;
}
__device__ __forceinline__ float bf2f(short h) {
  return __uint_as_float(((unsigned)(unsigned short)h) << 16);
}

// ---------------- utils ----------------
__device__ __forceinline__ float block_sum256(float v, float* red) {
#pragma unroll
  for (int off = 32; off; off >>= 1) v += __shfl_down(v, off);
  __syncthreads();
  if ((threadIdx.x & 63) == 0) red[threadIdx.x >> 6] = v;
  __syncthreads();
  return red[0] + red[1] + red[2] + red[3];
}

// ---------------- build sequence ----------------
__global__ __launch_bounds__(256) void build_img_kernel(
    const float* __restrict__ feats, const float* __restrict__ pe, float* __restrict__ x)
{
  __shared__ float T[64][65];
  int b = blockIdx.y;
  int s0 = blockIdx.x * 64;
  int tid = threadIdx.x;
  int r = tid >> 2;
  int c0 = (tid & 3) << 4;
  for (int d0 = 0; d0 < 768; d0 += 64) {
    const float* fp = feats + ((size_t)b*768 + d0 + r)*1024 + s0 + c0;
#pragma unroll
    for (int i = 0; i < 16; ++i) T[r][c0 + i] = fp[i];
    __syncthreads();
    float* xp = x + ((size_t)(b*SEQ0 + s0 + r))*768 + d0 + c0;
    const float* pp = pe + (size_t)(s0 + r)*768 + d0 + c0;
#pragma unroll
    for (int i = 0; i < 16; ++i) xp[i] = T[c0 + i][r] + pp[i];
    __syncthreads();
  }
}

__global__ __launch_bounds__(256) void build_misc_kernel(
    const float* __restrict__ past, const int* __restrict__ intent,
    const float* __restrict__ int_emb, const float* __restrict__ past_W,
    const float* __restrict__ past_b, const float* __restrict__ te,
    float* __restrict__ x)
{
  int b = blockIdx.y;
  int i = blockIdx.x;  // 0..16
  int tid = threadIdx.x;
  if (i == 0) {
    int idx = intent[b] - 1;
    idx = max(0, min(2, idx));
    for (int d = tid; d < 768; d += 256)
      x[((size_t)(b*SEQ0 + 1024))*768 + d] = int_emb[idx*768 + d];
  } else {
    int pi = i - 1;
    float p0 = past[(b*NPAST + pi)*6 + 0], p1 = past[(b*NPAST + pi)*6 + 1];
    float p2 = past[(b*NPAST + pi)*6 + 2], p3 = past[(b*NPAST + pi)*6 + 3];
    float p4 = past[(b*NPAST + pi)*6 + 4], p5 = past[(b*NPAST + pi)*6 + 5];
    for (int d = tid; d < 768; d += 256) {
      float s = past_b[d] + te[(size_t)pi*768 + d];
      s += p0*past_W[0*768 + d] + p1*past_W[1*768 + d] + p2*past_W[2*768 + d];
      s += p3*past_W[3*768 + d] + p4*past_W[4*768 + d] + p5*past_W[5*768 + d];
      x[((size_t)(b*SEQ0 + 1025 + pi))*768 + d] = s;
    }
  }
}

// ---------------- layernorm (prefill) ----------------
__global__ __launch_bounds__(256) void ln_kernel(
    const float* __restrict__ x, const float* __restrict__ g,
    const float* __restrict__ bta, float* __restrict__ h)
{
  __shared__ float red[4];
  size_t row = blockIdx.x;
  const float* xr = x + row*768;
  float* hr = h + row*768;
  int tid = threadIdx.x;
  float v0 = xr[tid], v1 = xr[tid+256], v2 = xr[tid+512];
  float m = block_sum256(v0+v1+v2, red) * (1.f/768.f);
  float d0 = v0-m, d1 = v1-m, d2 = v2-m;
  float var = block_sum256(d0*d0 + d1*d1 + d2*d2, red) * (1.f/768.f);
  float inv = rsqrtf(var + 1e-5f);
  hr[tid]     = d0*inv*g[tid]     + bta[tid];
  hr[tid+256] = d1*inv*g[tid+256] + bta[tid+256];
  hr[tid+512] = d2*inv*g[tid+512] + bta[tid+512];
}

// ---------------- W convert+transpose: fp32 [K][N] -> bf16 hi/lo [N][K] ----------------
__global__ __launch_bounds__(256) void wconv_kernel(
    const float* __restrict__ W, short* __restrict__ th, short* __restrict__ tl,
    int K, int N)
{
  __shared__ float T[64][68];
  int n0 = blockIdx.x * 64, k0 = blockIdx.y * 64;
  int t = threadIdx.x;
  int r = t >> 2, c0 = (t & 3) * 16;
  const float* src = W + (size_t)(k0 + r)*N + n0 + c0;
#pragma unroll
  for (int j = 0; j < 4; ++j) {
    f32x4 v = *(const f32x4*)(src + 4*j);
    T[r][c0 + 4*j + 0] = v.x; T[r][c0 + 4*j + 1] = v.y;
    T[r][c0 + 4*j + 2] = v.z; T[r][c0 + 4*j + 3] = v.w;
  }
  __syncthreads();
  bf16x8 h0, h1, l0, l1;
#pragma unroll
  for (int i = 0; i < 8; ++i) {
    float x = T[c0 + i][r];
    short hh = f2bf(x);
    h0[i] = hh; l0[i] = f2bf(x - bf2f(hh));
    float y = T[c0 + 8 + i][r];
    short hy = f2bf(y);
    h1[i] = hy; l1[i] = f2bf(y - bf2f(hy));
  }
  size_t dst = (size_t)(n0 + r)*K + k0 + c0;
  *(bf16x8*)(th + dst) = h0;
  *(bf16x8*)(th + dst + 8) = h1;
  *(bf16x8*)(tl + dst) = l0;
  *(bf16x8*)(tl + dst + 8) = l1;
}

// ---------------- MFMA GEMM: C(M,N) = A(M,K) @ W(K,N) + bias ----------------
__global__ __launch_bounds__(256) void gemm_mfma_kernel(
    const float* __restrict__ A, const short* __restrict__ Wh,
    const short* __restrict__ Wl, const float* __restrict__ bias,
    float* __restrict__ C, int M, int N, int K, int mode)
{
  __shared__ short As[2][128][40];
  __shared__ short Bs[2][128][40];
  int tid = threadIdx.x;
  int n0 = blockIdx.x * 128, m0 = blockIdx.y * 128;
  int wid = tid >> 6, l = tid & 63;
  int wm = wid >> 1, wn = wid & 1;
  int fr = l & 15, fk = (l >> 4) * 8;
  f32x4 acc[4][4] = {};
  int arow = tid >> 1, akh = (tid & 1) * 16;
  const float* aptr = A + (size_t)(m0 + arow)*K + akh;
  bool aval = (m0 + arow) < M;

  for (int k0 = 0; k0 < K; k0 += 32) {
    {
      float xv[16];
      if (aval) {
        const float* ap = aptr + k0;
#pragma unroll
        for (int j = 0; j < 4; ++j) {
          f32x4 v = *(const f32x4*)(ap + 4*j);
          xv[4*j+0] = v.x; xv[4*j+1] = v.y; xv[4*j+2] = v.z; xv[4*j+3] = v.w;
        }
      } else {
#pragma unroll
        for (int j = 0; j < 16; ++j) xv[j] = 0.f;
      }
      bf16x8 h0, h1, l0, l1;
#pragma unroll
      for (int e = 0; e < 8; ++e) {
        short hh = f2bf(xv[e]);
        h0[e] = hh; l0[e] = f2bf(xv[e] - bf2f(hh));
        short hy = f2bf(xv[8+e]);
        h1[e] = hy; l1[e] = f2bf(xv[8+e] - bf2f(hy));
      }
      *(bf16x8*)&As[0][arow][akh]     = h0;
      *(bf16x8*)&As[0][arow][akh + 8] = h1;
      *(bf16x8*)&As[1][arow][akh]     = l0;
      *(bf16x8*)&As[1][arow][akh + 8] = l1;
    }
#pragma unroll
    for (int cc = 0; cc < 2; ++cc) {
      int c = tid + cc*256;
      int row = c >> 2, woff = (c & 3) * 8;
      size_t src = (size_t)(n0 + row)*K + k0 + woff;
      *(bf16x8*)&Bs[0][row][woff] = *(const bf16x8*)(Wh + src);
      *(bf16x8*)&Bs[1][row][woff] = *(const bf16x8*)(Wl + src);
    }
    __syncthreads();
    bf16x8 af[4][2], bfv[4][2];
#pragma unroll
    for (int i = 0; i < 4; ++i) {
#pragma unroll
      for (int p = 0; p < 2; ++p) {
        af[i][p]  = *(const bf16x8*)&As[p][wm*64 + i*16 + fr][fk];
        bfv[i][p] = *(const bf16x8*)&Bs[p][wn*64 + i*16 + fr][fk];
      }
    }
#pragma unroll
    for (int im = 0; im < 4; ++im) {
#pragma unroll
      for (int in = 0; in < 4; ++in) {
        acc[im][in] = __builtin_amdgcn_mfma_f32_16x16x32_bf16(af[im][0], bfv[in][0], acc[im][in], 0, 0, 0);
        acc[im][in] = __builtin_amdgcn_mfma_f32_16x16x32_bf16(af[im][0], bfv[in][1], acc[im][in], 0, 0, 0);
        acc[im][in] = __builtin_amdgcn_mfma_f32_16x16x32_bf16(af[im][1], bfv[in][0], acc[im][in], 0, 0, 0);
      }
    }
    __syncthreads();
  }
#pragma unroll
  for (int in = 0; in < 4; ++in) {
    int n = n0 + wn*64 + in*16 + (l & 15);
    float bv = bias[n];
#pragma unroll
    for (int im = 0; im < 4; ++im) {
      f32x4 v = acc[im][in];
#pragma unroll
      for (int r = 0; r < 4; ++r) {
        int m = m0 + wm*64 + im*16 + (l >> 4)*4 + r;
        if (m < M) {
          float x = v[r] + bv;
          float* cp = &C[(size_t)m*N + n];
          if (mode == 1) x = fmaxf(x, 0.f);
          if (mode == 2) x += *cp;
          *cp = x;
        }
      }
    }
  }
}

// ---------------- scatter K/V into cache (prefill) ----------------
__global__ __launch_bounds__(256) void scatter_kv_kernel(
    const float* __restrict__ qkv, float* __restrict__ kc, float* __restrict__ vc,
    int S, int spad)
{
  int s = blockIdx.x, b = blockIdx.y;
  const float* row = qkv + ((size_t)b*S + s)*2304;
  int tid = threadIdx.x;
#pragma unroll
  for (int i = 0; i < 3; ++i) {
    int j = tid + i*256;
    int hh = j / 48, hd = j - hh*48;
    size_t dst = ((size_t)(b*16 + hh)*spad + s)*48 + hd;
    kc[dst] = row[768 + j];
    vc[dst] = row[1536 + j];
  }
}

// ---------------- causal flash attention (prefill), vectorized LDS ----------------
__global__ __launch_bounds__(256) void attn_prefill_kernel(
    const float* __restrict__ qkv, const float* __restrict__ Kc,
    const float* __restrict__ Vc, float* __restrict__ ctx, int S, int spad)
{
  __shared__ float Qs[32][49];
  __shared__ float Ks[64][52];   // row stride 208B, 16B aligned -> f32x4 over d
  __shared__ float Vt[48][68];   // transposed V; row stride 272B -> f32x4 over k
  __shared__ float Ps[32][68];   // row stride 272B -> f32x4 over k
  __shared__ float mrow[32], lrow[32], resc[32];
  int tid = threadIdx.x;
  int qt = blockIdx.x, h = blockIdx.y, b = blockIdx.z;
  int q0 = qt * 32;
  for (int i = tid; i < 32*48; i += 256) {
    int r = i / 48, d = i - r*48;
    int s = q0 + r;
    Qs[r][d] = (s < S) ? qkv[((size_t)(b*S + s))*2304 + h*48 + d] * SCALE_QK : 0.f;
  }
  if (tid < 32) { mrow[tid] = -INFINITY; lrow[tid] = 0.f; }
  float acc[2][3] = {};
  int pr0 = (tid >> 4) << 1;
  int pc  = tid & 15;
  int sr  = tid & 31;
  int skg = tid >> 5;
  int q_last = min(q0 + 31, S - 1);
  const float* Kb = Kc + (size_t)(b*16 + h)*spad*48;
  const float* Vb = Vc + (size_t)(b*16 + h)*spad*48;
  __syncthreads();
  float qreg[48];
#pragma unroll
  for (int d = 0; d < 48; ++d) qreg[d] = Qs[sr][d];
  for (int k0 = 0; k0 <= q_last; k0 += 64) {
    int kn = min(64, q_last - k0 + 1);
    for (int i = tid; i < 64*48; i += 256) {
      int r = i / 48, d = i - r*48;
      bool ok = r < kn;
      float kv = ok ? Kb[(size_t)(k0 + r)*48 + d] : 0.f;
      float vv = ok ? Vb[(size_t)(k0 + r)*48 + d] : 0.f;
      Ks[r][d] = kv;
      Vt[d][r] = vv;
    }
    __syncthreads();
    {
      int qg = q0 + sr;
#pragma unroll
      for (int jj = 0; jj < 8; ++jj) {
        int k = skg*8 + jj;
        const f32x4* kr = (const f32x4*)&Ks[k][0];
        float s = 0.f;
#pragma unroll
        for (int i = 0; i < 12; ++i) {
          f32x4 kv = kr[i];
          s += qreg[4*i+0]*kv.x + qreg[4*i+1]*kv.y + qreg[4*i+2]*kv.z + qreg[4*i+3]*kv.w;
        }
        int kg = k0 + k;
        bool valid = (qg < S) && (k < kn) && (kg <= qg);
        Ps[sr][k] = valid ? s : -INFINITY;
      }
    }
    __syncthreads();
    {
      int r = tid >> 3;
      int c0 = (tid & 7) * 8;
      float mold = mrow[r];
      float mx = mold;
      float pv[8];
#pragma unroll
      for (int j = 0; j < 8; ++j) { pv[j] = Ps[r][c0 + j]; mx = fmaxf(mx, pv[j]); }
#pragma unroll
      for (int m = 1; m < 8; m <<= 1) mx = fmaxf(mx, __shfl_xor(mx, m));
      float psum = 0.f;
      if (mx > -INFINITY) {
#pragma unroll
        for (int j = 0; j < 8; ++j) {
          float p = __expf(pv[j] - mx);
          Ps[r][c0 + j] = p;
          psum += p;
        }
      } else {
#pragma unroll
        for (int j = 0; j < 8; ++j) Ps[r][c0 + j] = 0.f;
      }
#pragma unroll
      for (int m = 1; m < 8; m <<= 1) psum += __shfl_xor(psum, m);
      if ((tid & 7) == 0) {
        if (mx > -INFINITY) {
          float rs = (mold > -INFINITY) ? __expf(mold - mx) : 0.f;
          lrow[r] = lrow[r]*rs + psum;
          mrow[r] = mx;
          resc[r] = rs;
        } else {
          resc[r] = 1.f;
        }
      }
    }
    __syncthreads();
#pragma unroll
    for (int rr = 0; rr < 2; ++rr) {
      int r = pr0 + rr;
      float f = resc[r];
      float a0 = acc[rr][0]*f, a1 = acc[rr][1]*f, a2 = acc[rr][2]*f;
      const f32x4* pr4 = (const f32x4*)&Ps[r][0];
      const f32x4* v0 = (const f32x4*)&Vt[pc*3+0][0];
      const f32x4* v1 = (const f32x4*)&Vt[pc*3+1][0];
      const f32x4* v2 = (const f32x4*)&Vt[pc*3+2][0];
#pragma unroll
      for (int k4 = 0; k4 < 16; ++k4) {
        f32x4 p4 = pr4[k4];
        f32x4 w0 = v0[k4], w1 = v1[k4], w2 = v2[k4];
        a0 += p4.x*w0.x + p4.y*w0.y + p4.z*w0.z + p4.w*w0.w;
        a1 += p4.x*w1.x + p4.y*w1.y + p4.z*w1.z + p4.w*w1.w;
        a2 += p4.x*w2.x + p4.y*w2.y + p4.z*w2.z + p4.w*w2.w;
      }
      acc[rr][0] = a0; acc[rr][1] = a1; acc[rr][2] = a2;
    }
    __syncthreads();
  }
#pragma unroll
  for (int rr = 0; rr < 2; ++rr) {
    int r = pr0 + rr, s = q0 + r;
    if (s < S) {
      float invl = 1.f / lrow[r];
      float* cp = &ctx[((size_t)(b*S + s))*768 + h*48 + pc*3];
      cp[0] = acc[rr][0]*invl; cp[1] = acc[rr][1]*invl; cp[2] = acc[rr][2]*invl;
    }
  }
}

// ================= decode phase kernels (launch-synced, all-CU grids) =================
struct DecParams {
  const float *qkv_W, *qkv_b, *out_W, *out_b;
  const float *ln1_g, *ln1_b, *ln2_g, *ln2_b;
  const float *ff1_W, *ff1_b, *ff2_W, *ff2_b;
  const float *dec1_W, *dec1_b, *dec2_W, *dec2_b;
  const float *pos_W, *pos_b, *time_e;
  const float *xlast;
  float *Kc, *Vc;
  float *x_tok, *x_in_buf, *x_mid_buf;
  float *qkv_part, *out_part, *ff1_part, *ff2_part, *dec1_part;
  float *outp;
};

// qkv GEMV partials: 36 n-tiles x 7 k-segs = 252 blocks. Also materializes x_in.
__global__ __launch_bounds__(256) void k_qkvA(DecParams P, int l) {
  int p = blockIdx.x;
  __shared__ float xin[2][768];
  __shared__ float hn[2][768];
  __shared__ float part[4][2][64];
  __shared__ float red[4];
  int tid = threadIdx.x;
  if (l == 0) {
    for (int i = tid; i < 1536; i += 256) ((float*)xin)[i] = P.x_tok[i];
  } else {
    for (int i = tid; i < 1536; i += 256) {
      float v = P.x_mid_buf[i];
#pragma unroll
      for (int s = 0; s < 21; ++s) v += P.ff2_part[s*1536 + i];
      ((float*)xin)[i] = v;
    }
  }
  __syncthreads();
  if (p == 0) {
    for (int i = tid; i < 1536; i += 256) P.x_in_buf[i] = ((float*)xin)[i];
  }
  const float* g  = P.ln1_g + l*768;
  const float* be = P.ln1_b + l*768;
#pragma unroll
  for (int b = 0; b < 2; ++b) {
    float v0 = xin[b][tid], v1 = xin[b][tid+256], v2 = xin[b][tid+512];
    float m = block_sum256(v0+v1+v2, red) * (1.f/768.f);
    float d0=v0-m, d1=v1-m, d2=v2-m;
    float var = block_sum256(d0*d0+d1*d1+d2*d2, red) * (1.f/768.f);
    float inv = rsqrtf(var + 1e-5f);
    hn[b][tid]     = d0*inv*g[tid]     + be[tid];
    hn[b][tid+256] = d1*inv*g[tid+256] + be[tid+256];
    hn[b][tid+512] = d2*inv*g[tid+512] + be[tid+512];
  }
  __syncthreads();
  int nt = p % 36, ks = p / 36;
  int k0 = (ks*768)/7, k1 = ((ks+1)*768)/7;
  int w = tid >> 6, lane = tid & 63;
  int kw0 = k0 + ((k1-k0)*w)/4, kw1 = k0 + ((k1-k0)*(w+1))/4;
  int n = nt*64 + lane;
  const float* wp = P.qkv_W + (size_t)l*768*2304 + n;
  float a0 = 0.f, a1 = 0.f;
#pragma unroll 4
  for (int k = kw0; k < kw1; ++k) {
    float w_ = wp[(size_t)k*2304];
    a0 += hn[0][k]*w_; a1 += hn[1][k]*w_;
  }
  part[w][0][lane] = a0; part[w][1][lane] = a1;
  __syncthreads();
  if (tid < 128) {
    int b = tid>>6, ln = tid&63;
    float s = part[0][b][ln]+part[1][b][ln]+part[2][b][ln]+part[3][b][ln];
    P.qkv_part[ks*4608 + b*2304 + nt*64 + ln] = s;
  }
}

// attention + out-proj partial: 32 blocks (b,h). Reduces qkv partials inline,
// writes KV cache at pos, flash attn, then rank-48 out-proj partial. (R5-verified)
__global__ __launch_bounds__(256) void k_attn_out(DecParams P, int l, int pos) {
  int p = blockIdx.x;
  int b = p >> 4, h = p & 15;
  __shared__ float qs[48], ksn[48], vsn[48], ctxs[48];
  __shared__ float redm[4], reds[4], aw[4][48];
  int tid = threadIdx.x;
  const float* qb = P.qkv_b + l*2304;
  if (tid < 48) {
    float q  = qb[h*48+tid];
    float kk = qb[768 + h*48+tid];
    float vv = qb[1536 + h*48+tid];
#pragma unroll
    for (int s = 0; s < 7; ++s) {
      const float* pp = P.qkv_part + s*4608 + b*2304;
      q  += pp[h*48+tid];
      kk += pp[768 + h*48+tid];
      vv += pp[1536 + h*48+tid];
    }
    size_t coff = (size_t)l*KVL_C + ((size_t)(b*16+h)*SPAD + pos)*48 + tid;
    P.Kc[coff] = kk;
    P.Vc[coff] = vv;
    qs[tid] = q * SCALE_QK; ksn[tid] = kk; vsn[tid] = vv;
  }
  __syncthreads();
  const float* Kb = P.Kc + (size_t)l*KVL_C + (size_t)(b*16+h)*SPAD*48;
  const float* Vb = P.Vc + (size_t)l*KVL_C + (size_t)(b*16+h)*SPAD*48;
  float ls[5];
  int cnt = 0;
  float lmax = -INFINITY;
  for (int k = tid; k < pos; k += 256) {
    const float4* kr = (const float4*)(Kb + (size_t)k*48);
    float s = 0.f;
#pragma unroll
    for (int i = 0; i < 12; ++i) {
      float4 kv = kr[i];
      s += qs[4*i]*kv.x + qs[4*i+1]*kv.y + qs[4*i+2]*kv.z + qs[4*i+3]*kv.w;
    }
    ls[cnt++] = s;
    lmax = fmaxf(lmax, s);
  }
  float s_extra = 0.f;
  if (tid == 0) {
#pragma unroll
    for (int d = 0; d < 48; ++d) s_extra += qs[d]*ksn[d];
    lmax = fmaxf(lmax, s_extra);
  }
#pragma unroll
  for (int off = 32; off; off >>= 1) lmax = fmaxf(lmax, __shfl_down(lmax, off));
  if ((tid & 63) == 0) redm[tid >> 6] = lmax;
  __syncthreads();
  float M = fmaxf(fmaxf(redm[0], redm[1]), fmaxf(redm[2], redm[3]));
  float lsum = 0.f;
  float4 a[12];
#pragma unroll
  for (int i = 0; i < 12; ++i) a[i] = make_float4(0.f, 0.f, 0.f, 0.f);
  cnt = 0;
  for (int k = tid; k < pos; k += 256) {
    float pr = __expf(ls[cnt++] - M);
    lsum += pr;
    const float4* vr = (const float4*)(Vb + (size_t)k*48);
#pragma unroll
    for (int i = 0; i < 12; ++i) {
      float4 vv = vr[i];
      a[i].x += pr*vv.x; a[i].y += pr*vv.y; a[i].z += pr*vv.z; a[i].w += pr*vv.w;
    }
  }
  if (tid == 0) {
    float pe = __expf(s_extra - M);
    lsum += pe;
#pragma unroll
    for (int i = 0; i < 12; ++i) {
      a[i].x += pe*vsn[4*i]; a[i].y += pe*vsn[4*i+1];
      a[i].z += pe*vsn[4*i+2]; a[i].w += pe*vsn[4*i+3];
    }
  }
  float tot = block_sum256(lsum, reds);
#pragma unroll
  for (int i = 0; i < 12; ++i) {
    float x0 = a[i].x, x1 = a[i].y, x2 = a[i].z, x3 = a[i].w;
#pragma unroll
    for (int off = 32; off; off >>= 1) {
      x0 += __shfl_down(x0, off); x1 += __shfl_down(x1, off);
      x2 += __shfl_down(x2, off); x3 += __shfl_down(x3, off);
    }
    if ((tid & 63) == 0) {
      int w = tid >> 6;
      aw[w][4*i] = x0; aw[w][4*i+1] = x1; aw[w][4*i+2] = x2; aw[w][4*i+3] = x3;
    }
  }
  __syncthreads();
  if (tid < 48) ctxs[tid] = (aw[0][tid]+aw[1][tid]+aw[2][tid]+aw[3][tid]) / tot;
  __syncthreads();
  const float* W = P.out_W + (size_t)l*768*768 + (size_t)h*48*768;
  for (int n = tid; n < 768; n += 256) {
    float acc = 0.f;
#pragma unroll
    for (int d = 0; d < 48; ++d) acc += ctxs[d]*W[(size_t)d*768 + n];
    P.out_part[h*1536 + b*768 + n] = acc;
  }
}

// ff1 GEMV partials: 48 n-tiles x 5 k-segs = 240 blocks. Materializes x_mid.
__global__ __launch_bounds__(256) void k_ff1A(DecParams P, int l) {
  int p = blockIdx.x;
  __shared__ float xm[2][768];
  __shared__ float hn[2][768];
  __shared__ float part[4][2][64];
  __shared__ float red[4];
  int tid = threadIdx.x;
  const float* ob = P.out_b + l*768;
  for (int i = tid; i < 1536; i += 256) {
    int b = i / 768, d = i - b*768;
    float v = P.x_in_buf[i] + ob[d];
#pragma unroll
    for (int s = 0; s < 16; ++s) v += P.out_part[s*1536 + i];
    xm[b][d] = v;
  }
  __syncthreads();
  if (p == 0) {
    for (int i = tid; i < 1536; i += 256) P.x_mid_buf[i] = ((float*)xm)[i];
  }
  const float* g  = P.ln2_g + l*768;
  const float* be = P.ln2_b + l*768;
#pragma unroll
  for (int b = 0; b < 2; ++b) {
    float v0 = xm[b][tid], v1 = xm[b][tid+256], v2 = xm[b][tid+512];
    float m = block_sum256(v0+v1+v2, red) * (1.f/768.f);
    float d0=v0-m, d1=v1-m, d2=v2-m;
    float var = block_sum256(d0*d0+d1*d1+d2*d2, red) * (1.f/768.f);
    float inv = rsqrtf(var + 1e-5f);
    hn[b][tid]     = d0*inv*g[tid]     + be[tid];
    hn[b][tid+256] = d1*inv*g[tid+256] + be[tid+256];
    hn[b][tid+512] = d2*inv*g[tid+512] + be[tid+512];
  }
  __syncthreads();
  int nt = p % 48, ks = p / 48;
  int k0 = (ks*768)/5, k1 = ((ks+1)*768)/5;
  int w = tid >> 6, lane = tid & 63;
  int kw0 = k0 + ((k1-k0)*w)/4, kw1 = k0 + ((k1-k0)*(w+1))/4;
  int n = nt*64 + lane;
  const float* wp = P.ff1_W + (size_t)l*768*3072 + n;
  float a0 = 0.f, a1 = 0.f;
#pragma unroll 4
  for (int k = kw0; k < kw1; ++k) {
    float w_ = wp[(size_t)k*3072];
    a0 += hn[0][k]*w_; a1 += hn[1][k]*w_;
  }
  part[w][0][lane] = a0; part[w][1][lane] = a1;
  __syncthreads();
  if (tid < 128) {
    int b = tid>>6, ln = tid&63;
    float s = part[0][b][ln]+part[1][b][ln]+part[2][b][ln]+part[3][b][ln];
    P.ff1_part[ks*6144 + b*3072 + nt*64 + ln] = s;
  }
}

// ff2 GEMV partials: 12 n-tiles x 21 k-segs = 252 blocks.
__global__ __launch_bounds__(256) void k_ff2A(DecParams P, int l) {
  int p = blockIdx.x;
  __shared__ float hseg[2][148];
  __shared__ float part[4][2][64];
  int tid = threadIdx.x;
  int nt = p % 12, ks = p / 12;
  int k0 = (ks*3072)/21, k1 = ((ks+1)*3072)/21;
  int kn = k1 - k0;
  const float* fb = P.ff1_b + l*3072;
  for (int i = tid; i < 2*kn; i += 256) {
    int b = i / kn, j = i - b*kn;
    float v = fb[k0+j];
#pragma unroll
    for (int s = 0; s < 5; ++s) v += P.ff1_part[s*6144 + b*3072 + k0 + j];
    hseg[b][j] = fmaxf(v, 0.f);
  }
  __syncthreads();
  int w = tid >> 6, lane = tid & 63;
  int jw0 = (kn*w)/4, jw1 = (kn*(w+1))/4;
  int n = nt*64 + lane;
  const float* wp = P.ff2_W + (size_t)l*3072*768 + n;
  float a0 = 0.f, a1 = 0.f;
#pragma unroll 4
  for (int j = jw0; j < jw1; ++j) {
    float w_ = wp[(size_t)(k0+j)*768];
    a0 += hseg[0][j]*w_; a1 += hseg[1][j]*w_;
  }
  part[w][0][lane] = a0; part[w][1][lane] = a1;
  __syncthreads();
  if (tid < 128) {
    int b = tid>>6, ln = tid&63;
    P.ff2_part[ks*1536 + b*768 + nt*64 + ln] =
        part[0][b][ln]+part[1][b][ln]+part[2][b][ln]+part[3][b][ln];
  }
}

// dec1 GEMV partials: 12 n-tiles x 21 k-segs = 252 blocks.
__global__ __launch_bounds__(256) void k_dec1A(DecParams P, int t) {
  int p = blockIdx.x;
  __shared__ float hseg[2][40];
  __shared__ float part[4][2][64];
  int tid = threadIdx.x;
  int nt = p % 12, ks = p / 12;
  int k0 = (ks*768)/21, k1 = ((ks+1)*768)/21;
  int kn = k1 - k0;
  for (int i = tid; i < 2*kn; i += 256) {
    int b = i / kn, j = i - b*kn;
    float v;
    if (t == 0) {
      v = P.xlast[(size_t)b*SEQ0*768 + k0 + j];
    } else {
      v = P.x_mid_buf[b*768 + k0 + j];
#pragma unroll
      for (int s = 0; s < 21; ++s) v += P.ff2_part[s*1536 + b*768 + k0 + j];
    }
    hseg[b][j] = v;
  }
  __syncthreads();
  int w = tid >> 6, lane = tid & 63;
  int jw0 = (kn*w)/4, jw1 = (kn*(w+1))/4;
  int n = nt*64 + lane;
  const float* wp = P.dec1_W + n;
  float a0 = 0.f, a1 = 0.f;
#pragma unroll 4
  for (int j = jw0; j < jw1; ++j) {
    float w_ = wp[(size_t)(k0+j)*768];
    a0 += hseg[0][j]*w_; a1 += hseg[1][j]*w_;
  }
  part[w][0][lane] = a0; part[w][1][lane] = a1;
  __syncthreads();
  if (tid < 128) {
    int b = tid>>6, ln = tid&63;
    P.dec1_part[ks*1536 + b*768 + nt*64 + ln] =
        part[0][b][ln]+part[1][b][ln]+part[2][b][ln]+part[3][b][ln];
  }
}

// head: reduce dec1 (+bias, gelu), dec2 dot, write pred + next token.
__global__ __launch_bounds__(256) void k_head2(DecParams P, int t, int write_next) {
  __shared__ float hd[2][768];
  __shared__ float ps[2][2];
  int tid = threadIdx.x;
  for (int i = tid; i < 1536; i += 256) {
    int b = i / 768, d = i - b*768;
    float v = P.dec1_b[d];
#pragma unroll
    for (int s = 0; s < 21; ++s) v += P.dec1_part[s*1536 + i];
    hd[b][d] = 0.5f*v*(1.f + erff(v*0.70710678118654752f));
  }
  __syncthreads();
  int w = tid >> 6, lane = tid & 63;
  int b = w >> 1, j = w & 1;
  float partial = 0.f;
  for (int k = lane; k < 768; k += 64) partial += hd[b][k] * P.dec2_W[k*2 + j];
#pragma unroll
  for (int off = 32; off; off >>= 1) partial += __shfl_down(partial, off);
  if (lane == 0) {
    float v = partial + P.dec2_b[j];
    ps[b][j] = v;
    P.outp[(b*TDEC + t)*2 + j] = v;
  }
  __syncthreads();
  if (write_next) {
    for (int i = tid; i < 1536; i += 256) {
      int b2 = i / 768, d = i - b2*768;
      P.x_tok[i] = ps[b2][0]*P.pos_W[d] + ps[b2][1]*P.pos_W[768 + d]
                 + P.pos_b[d] + P.time_e[(size_t)(NPAST + t)*768 + d];
    }
  }
}

// ---------------- host ----------------
extern "C" void kernel_launch(void* const* d_in, const int* in_sizes, int n_in,
                              void* d_out, int out_size, void* d_ws, size_t ws_size,
                              hipStream_t stream) {
  (void)in_sizes; (void)n_in; (void)out_size; (void)ws_size;
  const float* feats   = (const float*)d_in[0];
  const float* past    = (const float*)d_in[1];
  const int*   intent  = (const int*)d_in[2];
  const float* img_pos = (const float*)d_in[3];
  const float* time_e  = (const float*)d_in[4];
  const float* int_emb = (const float*)d_in[5];
  const float* past_W  = (const float*)d_in[6];
  const float* past_b  = (const float*)d_in[7];
  const float* pos_W   = (const float*)d_in[8];
  const float* pos_b   = (const float*)d_in[9];
  const float* ln1_g   = (const float*)d_in[10];
  const float* ln1_b   = (const float*)d_in[11];
  const float* qkv_W   = (const float*)d_in[12];
  const float* qkv_b   = (const float*)d_in[13];
  const float* out_W   = (const float*)d_in[14];
  const float* out_b   = (const float*)d_in[15];
  const float* ln2_g   = (const float*)d_in[16];
  const float* ln2_b   = (const float*)d_in[17];
  const float* ff1_W   = (const float*)d_in[18];
  const float* ff1_b   = (const float*)d_in[19];
  const float* ff2_W   = (const float*)d_in[20];
  const float* ff2_b   = (const float*)d_in[21];
  const float* dec1_W  = (const float*)d_in[22];
  const float* dec1_b  = (const float*)d_in[23];
  const float* dec2_W  = (const float*)d_in[24];
  const float* dec2_b  = (const float*)d_in[25];
  float* outp = (float*)d_out;

  float* ws = (float*)d_ws;
  size_t off = 0;
  float* xbuf = ws + off;   off += (size_t)MM*DD;
  float* hbuf = ws + off;   off += (size_t)MM*DD;
  float* ctxbuf = hbuf;  // alias: h consumed before attention writes ctx
  float* bigbuf = ws + off; off += (size_t)MM*3072;
  float* Kc = ws + off;     off += (size_t)LL*BB*HH*SPAD*HDIM;
  float* Vc = ws + off;     off += (size_t)LL*BB*HH*SPAD*HDIM;
  float* x_tok = ws + off;    off += BB*DD;
  float* x_in_buf = ws + off; off += BB*DD;
  float* x_mid_buf = ws + off; off += BB*DD;
  float* qkv_part = ws + off;  off += 7*2*2304;
  float* out_part = ws + off;  off += 16*2*768;
  float* ff1_part = ws + off;  off += 5*2*3072;
  float* ff2_part = ws + off;  off += 21*2*768;
  float* dec1_part = ws + off; off += 21*2*768;
  short* wt_h = (short*)(ws + off); off += (size_t)768*3072/2;
  short* wt_l = (short*)(ws + off); off += (size_t)768*3072/2;

  const size_t KVL = (size_t)BB*HH*SPAD*HDIM;

  // ---- build initial sequence ----
  build_img_kernel<<<dim3(NIMG/64, BB), 256, 0, stream>>>(feats, img_pos, xbuf);
  build_misc_kernel<<<dim3(17, BB), 256, 0, stream>>>(past, intent, int_emb, past_W, past_b, time_e, xbuf);

  // ---- prefill ----
  const int mtiles = (MM + 127) / 128;  // 17
  for (int l = 0; l < LL; ++l) {
    float* kcl = Kc + (size_t)l*KVL;
    float* vcl = Vc + (size_t)l*KVL;

    ln_kernel<<<MM, 256, 0, stream>>>(xbuf, ln1_g + l*DD, ln1_b + l*DD, hbuf);
    wconv_kernel<<<dim3(2304/64, 768/64), 256, 0, stream>>>(
        qkv_W + (size_t)l*DD*2304, wt_h, wt_l, DD, 2304);
    gemm_mfma_kernel<<<dim3(2304/128, mtiles), 256, 0, stream>>>(
        hbuf, wt_h, wt_l, qkv_b + l*2304, bigbuf, MM, 2304, DD, 0);

    scatter_kv_kernel<<<dim3(SEQ0, BB), 256, 0, stream>>>(bigbuf, kcl, vcl, SEQ0, SPAD);
    attn_prefill_kernel<<<dim3((SEQ0 + 31)/32, HH, BB), 256, 0, stream>>>(
        bigbuf, kcl, vcl, ctxbuf, SEQ0, SPAD);

    wconv_kernel<<<dim3(768/64, 768/64), 256, 0, stream>>>(
        out_W + (size_t)l*DD*DD, wt_h, wt_l, DD, 768);
    gemm_mfma_kernel<<<dim3(768/128, mtiles), 256, 0, stream>>>(
        ctxbuf, wt_h, wt_l, out_b + l*DD, xbuf, MM, 768, DD, 2);

    ln_kernel<<<MM, 256, 0, stream>>>(xbuf, ln2_g + l*DD, ln2_b + l*DD, hbuf);
    wconv_kernel<<<dim3(3072/64, 768/64), 256, 0, stream>>>(
        ff1_W + (size_t)l*DD*3072, wt_h, wt_l, DD, 3072);
    gemm_mfma_kernel<<<dim3(3072/128, mtiles), 256, 0, stream>>>(
        hbuf, wt_h, wt_l, ff1_b + l*3072, bigbuf, MM, 3072, DD, 1);

    wconv_kernel<<<dim3(768/64, 3072/64), 256, 0, stream>>>(
        ff2_W + (size_t)l*3072*DD, wt_h, wt_l, 3072, 768);
    gemm_mfma_kernel<<<dim3(768/128, mtiles), 256, 0, stream>>>(
        bigbuf, wt_h, wt_l, ff2_b + l*DD, xbuf, MM, 768, 3072, 2);
  }

  // ---- decode: launch-synced wide phase kernels (14/step) ----
  DecParams P;
  P.qkv_W = qkv_W; P.qkv_b = qkv_b; P.out_W = out_W; P.out_b = out_b;
  P.ln1_g = ln1_g; P.ln1_b = ln1_b; P.ln2_g = ln2_g; P.ln2_b = ln2_b;
  P.ff1_W = ff1_W; P.ff1_b = ff1_b; P.ff2_W = ff2_W; P.ff2_b = ff2_b;
  P.dec1_W = dec1_W; P.dec1_b = dec1_b; P.dec2_W = dec2_W; P.dec2_b = dec2_b;
  P.pos_W = pos_W; P.pos_b = pos_b; P.time_e = time_e;
  P.xlast = xbuf + (size_t)(SEQ0 - 1)*DD;
  P.Kc = Kc; P.Vc = Vc;
  P.x_tok = x_tok; P.x_in_buf = x_in_buf; P.x_mid_buf = x_mid_buf;
  P.qkv_part = qkv_part; P.out_part = out_part; P.ff1_part = ff1_part;
  P.ff2_part = ff2_part; P.dec1_part = dec1_part;
  P.outp = outp;

  // t = 0 head
  k_dec1A<<<252, 256, 0, stream>>>(P, 0);
  k_head2<<<1, 256, 0, stream>>>(P, 0, 1);
  // steps t = 1..19
  for (int t = 1; t < TDEC; ++t) {
    int pos = SEQ0 + t - 1;
    for (int l = 0; l < LL; ++l) {
      k_qkvA<<<252, 256, 0, stream>>>(P, l);
      k_attn_out<<<32, 256, 0, stream>>>(P, l, pos);
      k_ff1A<<<240, 256, 0, stream>>>(P, l);
      k_ff2A<<<252, 256, 0, stream>>>(P, l);
    }
    k_dec1A<<<252, 256, 0, stream>>>(P, t);
    k_head2<<<1, 256, 0, stream>>>(P, t, (t < TDEC - 1) ? 1 : 0);
  }
}

// Round 9
// 4819.606 us; speedup vs baseline: 1.2367x; 1.2367x over previous
//
#include <hip/hip_runtime.h>
#include <math.h>

#define BB 2
#define DD 768
#define HH 16
#define HDIM 48
#define LL 3
#define NIMG 1024
#define NPAST 16
#define TDEC 20
#define SEQ0 1041
#define SPAD 1064
#define MM (BB*SEQ0)
#define SCALE_QK 0.14433756729740643f
#define KVL_C ((size_t)BB*HH*SPAD*HDIM)

typedef __attribute__((ext_vector_type(4))) float f32x4;
typedef __attribute__((ext_vector_type(8))) short bf16x8;

__device__ __forceinline__ short f2bf(float x) {
  unsigned u = __float_as_uint(x);
  unsigned r = (u + 0x7FFFu + ((u >> 16) & 1u)) >> 16;
  return (short)r;
}
__device__ __forceinline__ float bf2f(short h) {
  return __uint_as_float(((unsigned)(unsigned short)h) << 16);
}

// ---------------- utils ----------------
__device__ __forceinline__ float block_sum256(float v, float* red) {
#pragma unroll
  for (int off = 32; off; off >>= 1) v += __shfl_down(v, off);
  __syncthreads();
  if ((threadIdx.x & 63) == 0) red[threadIdx.x >> 6] = v;
  __syncthreads();
  return red[0] + red[1] + red[2] + red[3];
}

// ---------------- build sequence ----------------
__global__ __launch_bounds__(256) void build_img_kernel(
    const float* __restrict__ feats, const float* __restrict__ pe, float* __restrict__ x)
{
  __shared__ float T[64][65];
  int b = blockIdx.y;
  int s0 = blockIdx.x * 64;
  int tid = threadIdx.x;
  int r = tid >> 2;
  int c0 = (tid & 3) << 4;
  for (int d0 = 0; d0 < 768; d0 += 64) {
    const float* fp = feats + ((size_t)b*768 + d0 + r)*1024 + s0 + c0;
#pragma unroll
    for (int i = 0; i < 16; ++i) T[r][c0 + i] = fp[i];
    __syncthreads();
    float* xp = x + ((size_t)(b*SEQ0 + s0 + r))*768 + d0 + c0;
    const float* pp = pe + (size_t)(s0 + r)*768 + d0 + c0;
#pragma unroll
    for (int i = 0; i < 16; ++i) xp[i] = T[c0 + i][r] + pp[i];
    __syncthreads();
  }
}

__global__ __launch_bounds__(256) void build_misc_kernel(
    const float* __restrict__ past, const int* __restrict__ intent,
    const float* __restrict__ int_emb, const float* __restrict__ past_W,
    const float* __restrict__ past_b, const float* __restrict__ te,
    float* __restrict__ x)
{
  int b = blockIdx.y;
  int i = blockIdx.x;  // 0..16
  int tid = threadIdx.x;
  if (i == 0) {
    int idx = intent[b] - 1;
    idx = max(0, min(2, idx));
    for (int d = tid; d < 768; d += 256)
      x[((size_t)(b*SEQ0 + 1024))*768 + d] = int_emb[idx*768 + d];
  } else {
    int pi = i - 1;
    float p0 = past[(b*NPAST + pi)*6 + 0], p1 = past[(b*NPAST + pi)*6 + 1];
    float p2 = past[(b*NPAST + pi)*6 + 2], p3 = past[(b*NPAST + pi)*6 + 3];
    float p4 = past[(b*NPAST + pi)*6 + 4], p5 = past[(b*NPAST + pi)*6 + 5];
    for (int d = tid; d < 768; d += 256) {
      float s = past_b[d] + te[(size_t)pi*768 + d];
      s += p0*past_W[0*768 + d] + p1*past_W[1*768 + d] + p2*past_W[2*768 + d];
      s += p3*past_W[3*768 + d] + p4*past_W[4*768 + d] + p5*past_W[5*768 + d];
      x[((size_t)(b*SEQ0 + 1025 + pi))*768 + d] = s;
    }
  }
}

// ---------------- layernorm (prefill) -> bf16 hi/lo output ----------------
__global__ __launch_bounds__(256) void ln_bf_kernel(
    const float* __restrict__ x, const float* __restrict__ g,
    const float* __restrict__ bta, short* __restrict__ hh, short* __restrict__ hl)
{
  __shared__ float red[4];
  size_t row = blockIdx.x;
  const float* xr = x + row*768;
  int tid = threadIdx.x;
  float v0 = xr[tid], v1 = xr[tid+256], v2 = xr[tid+512];
  float m = block_sum256(v0+v1+v2, red) * (1.f/768.f);
  float d0 = v0-m, d1 = v1-m, d2 = v2-m;
  float var = block_sum256(d0*d0 + d1*d1 + d2*d2, red) * (1.f/768.f);
  float inv = rsqrtf(var + 1e-5f);
  float o0 = d0*inv*g[tid]     + bta[tid];
  float o1 = d1*inv*g[tid+256] + bta[tid+256];
  float o2 = d2*inv*g[tid+512] + bta[tid+512];
  short h0 = f2bf(o0), h1 = f2bf(o1), h2 = f2bf(o2);
  size_t base = row*768;
  hh[base+tid]     = h0; hl[base+tid]     = f2bf(o0 - bf2f(h0));
  hh[base+tid+256] = h1; hl[base+tid+256] = f2bf(o1 - bf2f(h1));
  hh[base+tid+512] = h2; hl[base+tid+512] = f2bf(o2 - bf2f(h2));
}

// ---------------- W convert+transpose: fp32 [K][N] -> bf16 hi/lo [N][K] ----------------
__global__ __launch_bounds__(256) void wconv_kernel(
    const float* __restrict__ W, short* __restrict__ th, short* __restrict__ tl,
    int K, int N)
{
  __shared__ float T[64][68];
  int n0 = blockIdx.x * 64, k0 = blockIdx.y * 64;
  int t = threadIdx.x;
  int r = t >> 2, c0 = (t & 3) * 16;
  const float* src = W + (size_t)(k0 + r)*N + n0 + c0;
#pragma unroll
  for (int j = 0; j < 4; ++j) {
    f32x4 v = *(const f32x4*)(src + 4*j);
    T[r][c0 + 4*j + 0] = v.x; T[r][c0 + 4*j + 1] = v.y;
    T[r][c0 + 4*j + 2] = v.z; T[r][c0 + 4*j + 3] = v.w;
  }
  __syncthreads();
  bf16x8 h0, h1, l0, l1;
#pragma unroll
  for (int i = 0; i < 8; ++i) {
    float x = T[c0 + i][r];
    short hh = f2bf(x);
    h0[i] = hh; l0[i] = f2bf(x - bf2f(hh));
    float y = T[c0 + 8 + i][r];
    short hy = f2bf(y);
    h1[i] = hy; l1[i] = f2bf(y - bf2f(hy));
  }
  size_t dst = (size_t)(n0 + r)*K + k0 + c0;
  *(bf16x8*)(th + dst) = h0;
  *(bf16x8*)(th + dst + 8) = h1;
  *(bf16x8*)(tl + dst) = l0;
  *(bf16x8*)(tl + dst + 8) = l1;
}

// ---------------- MFMA GEMM with pre-split bf16 A ----------------
// A given as hi/lo bf16 [M][K]; W pre-converted bf16 [N][K] hi/lo.
// mode: 0 fp32 store, 1 relu + bf16-hi/lo store (Ch/Cl), 2 fp32 add,
//       3 fp32 store + KV-cache scatter (qkv layout, M=MM rows)
__global__ __launch_bounds__(256) void gemm_bf_kernel(
    const short* __restrict__ Ah, const short* __restrict__ Al,
    const short* __restrict__ Wh, const short* __restrict__ Wl,
    const float* __restrict__ bias, float* __restrict__ C,
    short* __restrict__ Ch, short* __restrict__ Cl,
    int M, int N, int K, int mode,
    float* __restrict__ kc, float* __restrict__ vc)
{
  __shared__ short As[2][128][40];
  __shared__ short Bs[2][128][40];
  int tid = threadIdx.x;
  int n0 = blockIdx.x * 128, m0 = blockIdx.y * 128;
  int wid = tid >> 6, l = tid & 63;
  int wm = wid >> 1, wn = wid & 1;
  int fr = l & 15, fk = (l >> 4) * 8;
  f32x4 acc[4][4] = {};
  int arow = tid >> 1, akh = (tid & 1) * 16;
  bool aval = (m0 + arow) < M;
  size_t abase = (size_t)(m0 + arow)*K + akh;

  for (int k0 = 0; k0 < K; k0 += 32) {
    if (aval) {
      size_t src = abase + k0;
      *(bf16x8*)&As[0][arow][akh]     = *(const bf16x8*)(Ah + src);
      *(bf16x8*)&As[0][arow][akh + 8] = *(const bf16x8*)(Ah + src + 8);
      *(bf16x8*)&As[1][arow][akh]     = *(const bf16x8*)(Al + src);
      *(bf16x8*)&As[1][arow][akh + 8] = *(const bf16x8*)(Al + src + 8);
    } else {
      bf16x8 z = {};
      *(bf16x8*)&As[0][arow][akh] = z; *(bf16x8*)&As[0][arow][akh + 8] = z;
      *(bf16x8*)&As[1][arow][akh] = z; *(bf16x8*)&As[1][arow][akh + 8] = z;
    }
#pragma unroll
    for (int cc = 0; cc < 2; ++cc) {
      int c = tid + cc*256;
      int row = c >> 2, woff = (c & 3) * 8;
      size_t src = (size_t)(n0 + row)*K + k0 + woff;
      *(bf16x8*)&Bs[0][row][woff] = *(const bf16x8*)(Wh + src);
      *(bf16x8*)&Bs[1][row][woff] = *(const bf16x8*)(Wl + src);
    }
    __syncthreads();
    bf16x8 af[4][2], bfv[4][2];
#pragma unroll
    for (int i = 0; i < 4; ++i) {
#pragma unroll
      for (int p = 0; p < 2; ++p) {
        af[i][p]  = *(const bf16x8*)&As[p][wm*64 + i*16 + fr][fk];
        bfv[i][p] = *(const bf16x8*)&Bs[p][wn*64 + i*16 + fr][fk];
      }
    }
#pragma unroll
    for (int im = 0; im < 4; ++im) {
#pragma unroll
      for (int in = 0; in < 4; ++in) {
        acc[im][in] = __builtin_amdgcn_mfma_f32_16x16x32_bf16(af[im][0], bfv[in][0], acc[im][in], 0, 0, 0);
        acc[im][in] = __builtin_amdgcn_mfma_f32_16x16x32_bf16(af[im][0], bfv[in][1], acc[im][in], 0, 0, 0);
        acc[im][in] = __builtin_amdgcn_mfma_f32_16x16x32_bf16(af[im][1], bfv[in][0], acc[im][in], 0, 0, 0);
      }
    }
    __syncthreads();
  }
#pragma unroll
  for (int in = 0; in < 4; ++in) {
    int n = n0 + wn*64 + in*16 + (l & 15);
    float bv = bias[n];
#pragma unroll
    for (int im = 0; im < 4; ++im) {
      f32x4 v = acc[im][in];
#pragma unroll
      for (int r = 0; r < 4; ++r) {
        int m = m0 + wm*64 + im*16 + (l >> 4)*4 + r;
        if (m < M) {
          float x = v[r] + bv;
          size_t off = (size_t)m*N + n;
          if (mode == 1) {
            x = fmaxf(x, 0.f);
            short hh = f2bf(x);
            Ch[off] = hh;
            Cl[off] = f2bf(x - bf2f(hh));
          } else if (mode == 2) {
            C[off] += x;
          } else {
            C[off] = x;
            if (mode == 3 && n >= 768) {
              int b = m / SEQ0, s = m - b*SEQ0;
              int j = n - 768;
              if (j < 768)
                kc[((size_t)(b*16 + j/48)*SPAD + s)*48 + (j % 48)] = x;
              else {
                j -= 768;
                vc[((size_t)(b*16 + j/48)*SPAD + s)*48 + (j % 48)] = x;
              }
            }
          }
        }
      }
    }
  }
}

// ---------------- causal flash attention (prefill), R7-proven body, bf16 ctx out ----------------
__global__ __launch_bounds__(256) void attn_prefill_kernel(
    const float* __restrict__ qkv, const float* __restrict__ Kc,
    const float* __restrict__ Vc, short* __restrict__ ctxh, short* __restrict__ ctxl,
    int S, int spad)
{
  __shared__ float Qs[32][49];
  __shared__ float Ks[64][49];
  __shared__ float Vs[64][49];
  __shared__ float Ps[32][65];
  __shared__ float mrow[32], lrow[32], resc[32];
  int tid = threadIdx.x;
  int qt = blockIdx.x, h = blockIdx.y, b = blockIdx.z;
  int q0 = qt * 32;
  for (int i = tid; i < 32*48; i += 256) {
    int r = i / 48, d = i - r*48;
    int s = q0 + r;
    Qs[r][d] = (s < S) ? qkv[((size_t)(b*S + s))*2304 + h*48 + d] * SCALE_QK : 0.f;
  }
  if (tid < 32) { mrow[tid] = -INFINITY; lrow[tid] = 0.f; }
  float acc[2][3] = {};
  int pr0 = (tid >> 4) << 1;
  int pc  = tid & 15;
  int sr  = tid & 31;
  int skg = tid >> 5;
  int q_last = min(q0 + 31, S - 1);
  const float* Kb = Kc + (size_t)(b*16 + h)*spad*48;
  const float* Vb = Vc + (size_t)(b*16 + h)*spad*48;
  __syncthreads();
  float qreg[48];
#pragma unroll
  for (int d = 0; d < 48; ++d) qreg[d] = Qs[sr][d];
  for (int k0 = 0; k0 <= q_last; k0 += 64) {
    int kn = min(64, q_last - k0 + 1);
    for (int i = tid; i < 64*48; i += 256) {
      int r = i / 48, d = i - r*48;
      bool ok = r < kn;
      Ks[r][d] = ok ? Kb[(size_t)(k0 + r)*48 + d] : 0.f;
      Vs[r][d] = ok ? Vb[(size_t)(k0 + r)*48 + d] : 0.f;
    }
    __syncthreads();
    {
      int qg = q0 + sr;
#pragma unroll
      for (int jj = 0; jj < 8; ++jj) {
        int k = skg*8 + jj;
        float s = 0.f;
#pragma unroll
        for (int d = 0; d < 48; ++d) s += qreg[d] * Ks[k][d];
        int kg = k0 + k;
        bool valid = (qg < S) && (k < kn) && (kg <= qg);
        Ps[sr][k] = valid ? s : -INFINITY;
      }
    }
    __syncthreads();
    {
      int r = tid >> 3;
      int c0 = (tid & 7) * 8;
      float mold = mrow[r];
      float mx = mold;
      float pv[8];
#pragma unroll
      for (int j = 0; j < 8; ++j) { pv[j] = Ps[r][c0 + j]; mx = fmaxf(mx, pv[j]); }
#pragma unroll
      for (int m = 1; m < 8; m <<= 1) mx = fmaxf(mx, __shfl_xor(mx, m));
      float psum = 0.f;
      if (mx > -INFINITY) {
#pragma unroll
        for (int j = 0; j < 8; ++j) {
          float p = __expf(pv[j] - mx);
          Ps[r][c0 + j] = p;
          psum += p;
        }
      } else {
#pragma unroll
        for (int j = 0; j < 8; ++j) Ps[r][c0 + j] = 0.f;
      }
#pragma unroll
      for (int m = 1; m < 8; m <<= 1) psum += __shfl_xor(psum, m);
      if ((tid & 7) == 0) {
        if (mx > -INFINITY) {
          float rs = (mold > -INFINITY) ? __expf(mold - mx) : 0.f;
          lrow[r] = lrow[r]*rs + psum;
          mrow[r] = mx;
          resc[r] = rs;
        } else {
          resc[r] = 1.f;
        }
      }
    }
    __syncthreads();
#pragma unroll
    for (int rr = 0; rr < 2; ++rr) {
      int r = pr0 + rr;
      float f = resc[r];
      float a0 = acc[rr][0]*f, a1 = acc[rr][1]*f, a2 = acc[rr][2]*f;
#pragma unroll 16
      for (int k = 0; k < 64; ++k) {
        float p = Ps[r][k];
        a0 += p * Vs[k][pc*3+0];
        a1 += p * Vs[k][pc*3+1];
        a2 += p * Vs[k][pc*3+2];
      }
      acc[rr][0] = a0; acc[rr][1] = a1; acc[rr][2] = a2;
    }
    __syncthreads();
  }
#pragma unroll
  for (int rr = 0; rr < 2; ++rr) {
    int r = pr0 + rr, s = q0 + r;
    if (s < S) {
      float invl = 1.f / lrow[r];
      size_t off = ((size_t)(b*S + s))*768 + h*48 + pc*3;
#pragma unroll
      for (int j = 0; j < 3; ++j) {
        float val = acc[rr][j]*invl;
        short hh = f2bf(val);
        ctxh[off + j] = hh;
        ctxl[off + j] = f2bf(val - bf2f(hh));
      }
    }
  }
}

// ================= decode phase kernels (exact R7 copies) =================
struct DecParams {
  const float *qkv_W, *qkv_b, *out_W, *out_b;
  const float *ln1_g, *ln1_b, *ln2_g, *ln2_b;
  const float *ff1_W, *ff1_b, *ff2_W, *ff2_b;
  const float *dec1_W, *dec1_b, *dec2_W, *dec2_b;
  const float *pos_W, *pos_b, *time_e;
  const float *xlast;
  float *Kc, *Vc;
  float *x_tok, *x_in_buf, *x_mid_buf;
  float *qkv_part, *out_part, *ff1_part, *ff2_part, *dec1_part;
  float *attn_m, *attn_l, *attn_o;
  float *outp;
};

// qkv GEMV partials: 36 n-tiles x 7 k-segs = 252 blocks. Also materializes x_in.
__global__ __launch_bounds__(256) void k_qkvA(DecParams P, int l) {
  int p = blockIdx.x;
  __shared__ float xin[2][768];
  __shared__ float hn[2][768];
  __shared__ float part[4][2][64];
  __shared__ float red[4];
  int tid = threadIdx.x;
  if (l == 0) {
    for (int i = tid; i < 1536; i += 256) ((float*)xin)[i] = P.x_tok[i];
  } else {
    for (int i = tid; i < 1536; i += 256) {
      float v = P.x_mid_buf[i];
#pragma unroll
      for (int s = 0; s < 21; ++s) v += P.ff2_part[s*1536 + i];
      ((float*)xin)[i] = v;
    }
  }
  __syncthreads();
  if (p == 0) {
    for (int i = tid; i < 1536; i += 256) P.x_in_buf[i] = ((float*)xin)[i];
  }
  const float* g  = P.ln1_g + l*768;
  const float* be = P.ln1_b + l*768;
#pragma unroll
  for (int b = 0; b < 2; ++b) {
    float v0 = xin[b][tid], v1 = xin[b][tid+256], v2 = xin[b][tid+512];
    float m = block_sum256(v0+v1+v2, red) * (1.f/768.f);
    float d0=v0-m, d1=v1-m, d2=v2-m;
    float var = block_sum256(d0*d0+d1*d1+d2*d2, red) * (1.f/768.f);
    float inv = rsqrtf(var + 1e-5f);
    hn[b][tid]     = d0*inv*g[tid]     + be[tid];
    hn[b][tid+256] = d1*inv*g[tid+256] + be[tid+256];
    hn[b][tid+512] = d2*inv*g[tid+512] + be[tid+512];
  }
  __syncthreads();
  int nt = p % 36, ks = p / 36;
  int k0 = (ks*768)/7, k1 = ((ks+1)*768)/7;
  int w = tid >> 6, lane = tid & 63;
  int kw0 = k0 + ((k1-k0)*w)/4, kw1 = k0 + ((k1-k0)*(w+1))/4;
  int n = nt*64 + lane;
  const float* wp = P.qkv_W + (size_t)l*768*2304 + n;
  float a0 = 0.f, a1 = 0.f;
#pragma unroll 4
  for (int k = kw0; k < kw1; ++k) {
    float w_ = wp[(size_t)k*2304];
    a0 += hn[0][k]*w_; a1 += hn[1][k]*w_;
  }
  part[w][0][lane] = a0; part[w][1][lane] = a1;
  __syncthreads();
  if (tid < 128) {
    int b = tid>>6, ln = tid&63;
    float s = part[0][b][ln]+part[1][b][ln]+part[2][b][ln]+part[3][b][ln];
    P.qkv_part[ks*4608 + b*2304 + nt*64 + ln] = s;
  }
}

// attention flash-partials: 256 blocks (b, h, seg). seg 7 also writes new K/V.
__global__ __launch_bounds__(256) void k_attn(DecParams P, int l, int pos) {
  __shared__ float qs[48], ksn[48], vsn[48];
  __shared__ float redm[4], reds[4];
  __shared__ float aw[4][48];
  int p = blockIdx.x;
  int b = p >> 7, h = (p >> 3) & 15, s = p & 7;
  int tid = threadIdx.x;
  const float* qb = P.qkv_b + l*2304;
  if (tid < 48) {
    float q  = qb[h*48+tid];
    float kk = qb[768 + h*48+tid];
    float vv = qb[1536 + h*48+tid];
#pragma unroll
    for (int ss = 0; ss < 7; ++ss) {
      const float* pp = P.qkv_part + ss*4608 + b*2304;
      q  += pp[h*48+tid];
      kk += pp[768 + h*48+tid];
      vv += pp[1536 + h*48+tid];
    }
    if (s == 7) {
      size_t coff = (size_t)l*KVL_C + ((size_t)(b*16+h)*SPAD + pos)*48 + tid;
      P.Kc[coff] = kk;
      P.Vc[coff] = vv;
    }
    qs[tid] = q * SCALE_QK; ksn[tid] = kk; vsn[tid] = vv;
  }
  __syncthreads();
  int CH = (pos + 7) >> 3;
  int r0 = s*CH, r1 = min(r0 + CH, pos);
  int nold = r1 - r0;
  bool is_new = (s == 7) && (tid == nold);
  bool active = (tid < nold) || is_new;
  const float* Kb = P.Kc + (size_t)l*KVL_C + (size_t)(b*16+h)*SPAD*48;
  const float* Vb = P.Vc + (size_t)l*KVL_C + (size_t)(b*16+h)*SPAD*48;
  float sc = -INFINITY;
  if (tid < nold) {
    const float4* kr = (const float4*)(Kb + (size_t)(r0+tid)*48);
    float ssum = 0.f;
#pragma unroll
    for (int i = 0; i < 12; ++i) {
      float4 kv = kr[i];
      ssum += qs[4*i]*kv.x + qs[4*i+1]*kv.y + qs[4*i+2]*kv.z + qs[4*i+3]*kv.w;
    }
    sc = ssum;
  } else if (is_new) {
    float ssum = 0.f;
#pragma unroll
    for (int d = 0; d < 48; ++d) ssum += qs[d]*ksn[d];
    sc = ssum;
  }
  float mx = sc;
#pragma unroll
  for (int o2 = 32; o2; o2 >>= 1) mx = fmaxf(mx, __shfl_down(mx, o2));
  if ((tid & 63) == 0) redm[tid >> 6] = mx;
  __syncthreads();
  float M = fmaxf(fmaxf(redm[0], redm[1]), fmaxf(redm[2], redm[3]));
  float pr = active ? __expf(sc - M) : 0.f;
  float lsum = block_sum256(pr, reds);
  float4 a[12];
  if (tid < nold) {
    const float4* vr = (const float4*)(Vb + (size_t)(r0+tid)*48);
#pragma unroll
    for (int i = 0; i < 12; ++i) {
      float4 vv = vr[i];
      a[i].x = pr*vv.x; a[i].y = pr*vv.y; a[i].z = pr*vv.z; a[i].w = pr*vv.w;
    }
  } else if (is_new) {
#pragma unroll
    for (int i = 0; i < 12; ++i) {
      a[i].x = pr*vsn[4*i]; a[i].y = pr*vsn[4*i+1];
      a[i].z = pr*vsn[4*i+2]; a[i].w = pr*vsn[4*i+3];
    }
  } else {
#pragma unroll
    for (int i = 0; i < 12; ++i) a[i] = make_float4(0.f,0.f,0.f,0.f);
  }
#pragma unroll
  for (int i = 0; i < 12; ++i) {
    float x0=a[i].x, x1=a[i].y, x2=a[i].z, x3=a[i].w;
#pragma unroll
    for (int o2 = 32; o2; o2 >>= 1) {
      x0 += __shfl_down(x0, o2); x1 += __shfl_down(x1, o2);
      x2 += __shfl_down(x2, o2); x3 += __shfl_down(x3, o2);
    }
    if ((tid & 63) == 0) {
      int w = tid >> 6;
      aw[w][4*i] = x0; aw[w][4*i+1] = x1; aw[w][4*i+2] = x2; aw[w][4*i+3] = x3;
    }
  }
  __syncthreads();
  int idx = (b*16 + h)*8 + s;
  if (tid == 0) { P.attn_m[idx] = M; P.attn_l[idx] = lsum; }
  if (tid < 48) P.attn_o[idx*48 + tid] = aw[0][tid]+aw[1][tid]+aw[2][tid]+aw[3][tid];
}

// out-proj: 48 blocks (6 n-tiles x 8 k-segs). Combines attn segs for its k-slice.
__global__ __launch_bounds__(256) void k_out(DecParams P, int l) {
  int p = blockIdx.x;
  __shared__ float ctx_s[2][96];
  __shared__ float opart[4][2][64][2];
  int nt = p / 8, ks = p % 8;
  int k0 = ks * 96;
  int tid = threadIdx.x;
  if (tid < 192) {
    int b = tid / 96, dl = tid % 96;
    int d = k0 + dl;
    int h = d / 48, dd = d % 48;
    int base = (b*16 + h)*8;
    float M = -INFINITY;
#pragma unroll
    for (int s2 = 0; s2 < 8; ++s2) M = fmaxf(M, P.attn_m[base+s2]);
    float L = 0.f, o = 0.f;
#pragma unroll
    for (int s2 = 0; s2 < 8; ++s2) {
      float e = __expf(P.attn_m[base+s2] - M);
      L += P.attn_l[base+s2]*e;
      o += P.attn_o[(base+s2)*48 + dd]*e;
    }
    ctx_s[b][dl] = o / L;
  }
  __syncthreads();
  int w = tid >> 6, lane = tid & 63;
  int n0 = nt * 128;
  const float* W = P.out_W + (size_t)l*768*768;
  float a00=0.f, a01=0.f, a10=0.f, a11=0.f;
#pragma unroll 4
  for (int j = w*24; j < w*24 + 24; ++j) {
    int kk = k0 + j;
    float2 wv = *(const float2*)&W[(size_t)kk*768 + n0 + lane*2];
    float c0 = ctx_s[0][j], c1 = ctx_s[1][j];
    a00 += c0*wv.x; a01 += c0*wv.y;
    a10 += c1*wv.x; a11 += c1*wv.y;
  }
  opart[w][0][lane][0] = a00; opart[w][0][lane][1] = a01;
  opart[w][1][lane][0] = a10; opart[w][1][lane][1] = a11;
  __syncthreads();
  {
    int b = tid >> 7, idx = tid & 127;
    int l2 = idx >> 1, c = idx & 1;
    float v = opart[0][b][l2][c] + opart[1][b][l2][c]
            + opart[2][b][l2][c] + opart[3][b][l2][c];
    P.out_part[ks*1536 + b*768 + n0 + idx] = v;
  }
}

// ff1 GEMV partials: 48 n-tiles x 5 k-segs = 240 blocks. Materializes x_mid.
__global__ __launch_bounds__(256) void k_ff1A(DecParams P, int l) {
  int p = blockIdx.x;
  __shared__ float xm[2][768];
  __shared__ float hn[2][768];
  __shared__ float part[4][2][64];
  __shared__ float red[4];
  int tid = threadIdx.x;
  const float* ob = P.out_b + l*768;
  for (int i = tid; i < 1536; i += 256) {
    int b = i / 768, d = i - b*768;
    float v = P.x_in_buf[i] + ob[d];
#pragma unroll
    for (int s = 0; s < 8; ++s) v += P.out_part[s*1536 + i];
    xm[b][d] = v;
  }
  __syncthreads();
  if (p == 0) {
    for (int i = tid; i < 1536; i += 256) P.x_mid_buf[i] = ((float*)xm)[i];
  }
  const float* g  = P.ln2_g + l*768;
  const float* be = P.ln2_b + l*768;
#pragma unroll
  for (int b = 0; b < 2; ++b) {
    float v0 = xm[b][tid], v1 = xm[b][tid+256], v2 = xm[b][tid+512];
    float m = block_sum256(v0+v1+v2, red) * (1.f/768.f);
    float d0=v0-m, d1=v1-m, d2=v2-m;
    float var = block_sum256(d0*d0+d1*d1+d2*d2, red) * (1.f/768.f);
    float inv = rsqrtf(var + 1e-5f);
    hn[b][tid]     = d0*inv*g[tid]     + be[tid];
    hn[b][tid+256] = d1*inv*g[tid+256] + be[tid+256];
    hn[b][tid+512] = d2*inv*g[tid+512] + be[tid+512];
  }
  __syncthreads();
  int nt = p % 48, ks = p / 48;
  int k0 = (ks*768)/5, k1 = ((ks+1)*768)/5;
  int w = tid >> 6, lane = tid & 63;
  int kw0 = k0 + ((k1-k0)*w)/4, kw1 = k0 + ((k1-k0)*(w+1))/4;
  int n = nt*64 + lane;
  const float* wp = P.ff1_W + (size_t)l*768*3072 + n;
  float a0 = 0.f, a1 = 0.f;
#pragma unroll 4
  for (int k = kw0; k < kw1; ++k) {
    float w_ = wp[(size_t)k*3072];
    a0 += hn[0][k]*w_; a1 += hn[1][k]*w_;
  }
  part[w][0][lane] = a0; part[w][1][lane] = a1;
  __syncthreads();
  if (tid < 128) {
    int b = tid>>6, ln = tid&63;
    float s = part[0][b][ln]+part[1][b][ln]+part[2][b][ln]+part[3][b][ln];
    P.ff1_part[ks*6144 + b*3072 + nt*64 + ln] = s;
  }
}

// ff2 GEMV partials: 12 n-tiles x 21 k-segs = 252 blocks.
__global__ __launch_bounds__(256) void k_ff2A(DecParams P, int l) {
  int p = blockIdx.x;
  __shared__ float hseg[2][148];
  __shared__ float part[4][2][64];
  int tid = threadIdx.x;
  int nt = p % 12, ks = p / 12;
  int k0 = (ks*3072)/21, k1 = ((ks+1)*3072)/21;
  int kn = k1 - k0;
  const float* fb = P.ff1_b + l*3072;
  for (int i = tid; i < 2*kn; i += 256) {
    int b = i / kn, j = i - b*kn;
    float v = fb[k0+j];
#pragma unroll
    for (int s = 0; s < 5; ++s) v += P.ff1_part[s*6144 + b*3072 + k0 + j];
    hseg[b][j] = fmaxf(v, 0.f);
  }
  __syncthreads();
  int w = tid >> 6, lane = tid & 63;
  int jw0 = (kn*w)/4, jw1 = (kn*(w+1))/4;
  int n = nt*64 + lane;
  const float* wp = P.ff2_W + (size_t)l*3072*768 + n;
  float a0 = 0.f, a1 = 0.f;
#pragma unroll 4
  for (int j = jw0; j < jw1; ++j) {
    float w_ = wp[(size_t)(k0+j)*768];
    a0 += hseg[0][j]*w_; a1 += hseg[1][j]*w_;
  }
  part[w][0][lane] = a0; part[w][1][lane] = a1;
  __syncthreads();
  if (tid < 128) {
    int b = tid>>6, ln = tid&63;
    P.ff2_part[ks*1536 + b*768 + nt*64 + ln] =
        part[0][b][ln]+part[1][b][ln]+part[2][b][ln]+part[3][b][ln];
  }
}

// dec1 GEMV partials: 12 n-tiles x 21 k-segs = 252 blocks.
__global__ __launch_bounds__(256) void k_dec1A(DecParams P, int t) {
  int p = blockIdx.x;
  __shared__ float hseg[2][40];
  __shared__ float part[4][2][64];
  int tid = threadIdx.x;
  int nt = p % 12, ks = p / 12;
  int k0 = (ks*768)/21, k1 = ((ks+1)*768)/21;
  int kn = k1 - k0;
  for (int i = tid; i < 2*kn; i += 256) {
    int b = i / kn, j = i - b*kn;
    float v;
    if (t == 0) {
      v = P.xlast[(size_t)b*SEQ0*768 + k0 + j];
    } else {
      v = P.x_mid_buf[b*768 + k0 + j];
#pragma unroll
      for (int s = 0; s < 21; ++s) v += P.ff2_part[s*1536 + b*768 + k0 + j];
    }
    hseg[b][j] = v;
  }
  __syncthreads();
  int w = tid >> 6, lane = tid & 63;
  int jw0 = (kn*w)/4, jw1 = (kn*(w+1))/4;
  int n = nt*64 + lane;
  const float* wp = P.dec1_W + n;
  float a0 = 0.f, a1 = 0.f;
#pragma unroll 4
  for (int j = jw0; j < jw1; ++j) {
    float w_ = wp[(size_t)(k0+j)*768];
    a0 += hseg[0][j]*w_; a1 += hseg[1][j]*w_;
  }
  part[w][0][lane] = a0; part[w][1][lane] = a1;
  __syncthreads();
  if (tid < 128) {
    int b = tid>>6, ln = tid&63;
    P.dec1_part[ks*1536 + b*768 + nt*64 + ln] =
        part[0][b][ln]+part[1][b][ln]+part[2][b][ln]+part[3][b][ln];
  }
}

// head: reduce dec1 (+bias, gelu), dec2 dot, write pred + next token.
__global__ __launch_bounds__(256) void k_head2(DecParams P, int t, int write_next) {
  __shared__ float hd[2][768];
  __shared__ float ps[2][2];
  int tid = threadIdx.x;
  for (int i = tid; i < 1536; i += 256) {
    int b = i / 768, d = i - b*768;
    float v = P.dec1_b[d];
#pragma unroll
    for (int s = 0; s < 21; ++s) v += P.dec1_part[s*1536 + i];
    hd[b][d] = 0.5f*v*(1.f + erff(v*0.70710678118654752f));
  }
  __syncthreads();
  int w = tid >> 6, lane = tid & 63;
  int b = w >> 1, j = w & 1;
  float partial = 0.f;
  for (int k = lane; k < 768; k += 64) partial += hd[b][k] * P.dec2_W[k*2 + j];
#pragma unroll
  for (int off = 32; off; off >>= 1) partial += __shfl_down(partial, off);
  if (lane == 0) {
    float v = partial + P.dec2_b[j];
    ps[b][j] = v;
    P.outp[(b*TDEC + t)*2 + j] = v;
  }
  __syncthreads();
  if (write_next) {
    for (int i = tid; i < 1536; i += 256) {
      int b2 = i / 768, d = i - b2*768;
      P.x_tok[i] = ps[b2][0]*P.pos_W[d] + ps[b2][1]*P.pos_W[768 + d]
                 + P.pos_b[d] + P.time_e[(size_t)(NPAST + t)*768 + d];
    }
  }
}

// ---------------- host ----------------
extern "C" void kernel_launch(void* const* d_in, const int* in_sizes, int n_in,
                              void* d_out, int out_size, void* d_ws, size_t ws_size,
                              hipStream_t stream) {
  (void)in_sizes; (void)n_in; (void)out_size; (void)ws_size;
  const float* feats   = (const float*)d_in[0];
  const float* past    = (const float*)d_in[1];
  const int*   intent  = (const int*)d_in[2];
  const float* img_pos = (const float*)d_in[3];
  const float* time_e  = (const float*)d_in[4];
  const float* int_emb = (const float*)d_in[5];
  const float* past_W  = (const float*)d_in[6];
  const float* past_b  = (const float*)d_in[7];
  const float* pos_W   = (const float*)d_in[8];
  const float* pos_b   = (const float*)d_in[9];
  const float* ln1_g   = (const float*)d_in[10];
  const float* ln1_b   = (const float*)d_in[11];
  const float* qkv_W   = (const float*)d_in[12];
  const float* qkv_b   = (const float*)d_in[13];
  const float* out_W   = (const float*)d_in[14];
  const float* out_b   = (const float*)d_in[15];
  const float* ln2_g   = (const float*)d_in[16];
  const float* ln2_b   = (const float*)d_in[17];
  const float* ff1_W   = (const float*)d_in[18];
  const float* ff1_b   = (const float*)d_in[19];
  const float* ff2_W   = (const float*)d_in[20];
  const float* ff2_b   = (const float*)d_in[21];
  const float* dec1_W  = (const float*)d_in[22];
  const float* dec1_b  = (const float*)d_in[23];
  const float* dec2_W  = (const float*)d_in[24];
  const float* dec2_b  = (const float*)d_in[25];
  float* outp = (float*)d_out;

  float* ws = (float*)d_ws;
  size_t off = 0;
  float* xbuf = ws + off;   off += (size_t)MM*DD;
  // hh/hl (bf16) occupy the old hbuf footprint; also reused as ctxh/ctxl
  short* hh = (short*)(ws + off); off += (size_t)MM*DD/2;
  short* hl = (short*)(ws + off); off += (size_t)MM*DD/2;
  float* bigbuf = ws + off; off += (size_t)MM*3072;   // fp32 qkv out; later bf16 ff1 hi/lo
  short* bigh = (short*)bigbuf;
  short* bigl = bigh + (size_t)MM*3072;
  float* Kc = ws + off;     off += (size_t)LL*BB*HH*SPAD*HDIM;
  float* Vc = ws + off;     off += (size_t)LL*BB*HH*SPAD*HDIM;
  float* x_tok = ws + off;    off += BB*DD;
  float* x_in_buf = ws + off; off += BB*DD;
  float* x_mid_buf = ws + off; off += BB*DD;
  float* qkv_part = ws + off;  off += 7*2*2304;
  float* out_part = ws + off;  off += 8*2*768;
  float* ff1_part = ws + off;  off += 5*2*3072;
  float* ff2_part = ws + off;  off += 21*2*768;
  float* dec1_part = ws + off; off += 21*2*768;
  float* attn_m = ws + off;    off += 2*16*8;
  float* attn_l = ws + off;    off += 2*16*8;
  float* attn_o = ws + off;    off += 2*16*8*48;
  short* wt_h = (short*)(ws + off); off += (size_t)768*3072/2;
  short* wt_l = (short*)(ws + off); off += (size_t)768*3072/2;

  const size_t KVL = (size_t)BB*HH*SPAD*HDIM;

  // ---- build initial sequence ----
  build_img_kernel<<<dim3(NIMG/64, BB), 256, 0, stream>>>(feats, img_pos, xbuf);
  build_misc_kernel<<<dim3(17, BB), 256, 0, stream>>>(past, intent, int_emb, past_W, past_b, time_e, xbuf);

  // ---- prefill ----
  const int mtiles = (MM + 127) / 128;  // 17
  for (int l = 0; l < LL; ++l) {
    float* kcl = Kc + (size_t)l*KVL;
    float* vcl = Vc + (size_t)l*KVL;

    ln_bf_kernel<<<MM, 256, 0, stream>>>(xbuf, ln1_g + l*DD, ln1_b + l*DD, hh, hl);
    wconv_kernel<<<dim3(2304/64, 768/64), 256, 0, stream>>>(
        qkv_W + (size_t)l*DD*2304, wt_h, wt_l, DD, 2304);
    gemm_bf_kernel<<<dim3(2304/128, mtiles), 256, 0, stream>>>(
        hh, hl, wt_h, wt_l, qkv_b + l*2304, bigbuf, nullptr, nullptr,
        MM, 2304, DD, 3, kcl, vcl);

    attn_prefill_kernel<<<dim3((SEQ0 + 31)/32, HH, BB), 256, 0, stream>>>(
        bigbuf, kcl, vcl, hh, hl, SEQ0, SPAD);

    wconv_kernel<<<dim3(768/64, 768/64), 256, 0, stream>>>(
        out_W + (size_t)l*DD*DD, wt_h, wt_l, DD, 768);
    gemm_bf_kernel<<<dim3(768/128, mtiles), 256, 0, stream>>>(
        hh, hl, wt_h, wt_l, out_b + l*DD, xbuf, nullptr, nullptr,
        MM, 768, DD, 2, nullptr, nullptr);

    ln_bf_kernel<<<MM, 256, 0, stream>>>(xbuf, ln2_g + l*DD, ln2_b + l*DD, hh, hl);
    wconv_kernel<<<dim3(3072/64, 768/64), 256, 0, stream>>>(
        ff1_W + (size_t)l*DD*3072, wt_h, wt_l, DD, 3072);
    gemm_bf_kernel<<<dim3(3072/128, mtiles), 256, 0, stream>>>(
        hh, hl, wt_h, wt_l, ff1_b + l*3072, nullptr, bigh, bigl,
        MM, 3072, DD, 1, nullptr, nullptr);

    wconv_kernel<<<dim3(768/64, 3072/64), 256, 0, stream>>>(
        ff2_W + (size_t)l*3072*DD, wt_h, wt_l, 3072, 768);
    gemm_bf_kernel<<<dim3(768/128, mtiles), 256, 0, stream>>>(
        bigh, bigl, wt_h, wt_l, ff2_b + l*DD, xbuf, nullptr, nullptr,
        MM, 768, 3072, 2, nullptr, nullptr);
  }

  // ---- decode: launch-synced wide phase kernels (exact R7) ----
  DecParams P;
  P.qkv_W = qkv_W; P.qkv_b = qkv_b; P.out_W = out_W; P.out_b = out_b;
  P.ln1_g = ln1_g; P.ln1_b = ln1_b; P.ln2_g = ln2_g; P.ln2_b = ln2_b;
  P.ff1_W = ff1_W; P.ff1_b = ff1_b; P.ff2_W = ff2_W; P.ff2_b = ff2_b;
  P.dec1_W = dec1_W; P.dec1_b = dec1_b; P.dec2_W = dec2_W; P.dec2_b = dec2_b;
  P.pos_W = pos_W; P.pos_b = pos_b; P.time_e = time_e;
  P.xlast = xbuf + (size_t)(SEQ0 - 1)*DD;
  P.Kc = Kc; P.Vc = Vc;
  P.x_tok = x_tok; P.x_in_buf = x_in_buf; P.x_mid_buf = x_mid_buf;
  P.qkv_part = qkv_part; P.out_part = out_part; P.ff1_part = ff1_part;
  P.ff2_part = ff2_part; P.dec1_part = dec1_part;
  P.attn_m = attn_m; P.attn_l = attn_l; P.attn_o = attn_o;
  P.outp = outp;

  // t = 0 head
  k_dec1A<<<252, 256, 0, stream>>>(P, 0);
  k_head2<<<1, 256, 0, stream>>>(P, 0, 1);
  // steps t = 1..19
  for (int t = 1; t < TDEC; ++t) {
    int pos = SEQ0 + t - 1;
    for (int l = 0; l < LL; ++l) {
      k_qkvA<<<252, 256, 0, stream>>>(P, l);
      k_attn<<<256, 256, 0, stream>>>(P, l, pos);
      k_out<<<48, 256, 0, stream>>>(P, l);
      k_ff1A<<<240, 256, 0, stream>>>(P, l);
      k_ff2A<<<252, 256, 0, stream>>>(P, l);
    }
    k_dec1A<<<252, 256, 0, stream>>>(P, t);
    k_head2<<<1, 256, 0, stream>>>(P, t, (t < TDEC - 1) ? 1 : 0);
  }
}